// Round 2
// baseline (77.388 us; speedup 1.0000x reference)
//
#include <hip/hip_runtime.h>
#include <math.h>

// Problem constants (from reference)
#define N_PRED 1000
#define M_BOX  2000
#define K_PASS 10
#define C_CLS  80
#define EPS_IOU 1e-7f

#define T_PRED 16                              // preds per block (amortize box reads)
#define NT ((N_PRED + T_PRED - 1) / T_PRED)    // 63 tiles
#define WAVES 4
#define BLK (WAVES * 64)
#define MCHUNKS ((M_BOX + 63) >> 6)            // 32
#define IDX_INF 0x7fffffff

// Kernel 1: block = (tile of 16 preds) x (pass k). 630 blocks x 256 thr.
// All 4 waves cooperatively scan the box prefix [0, roundup(maxn+1,64)) in
// wave-strided 64-box chunks with NO data-dependent break: "first match" ==
// min matched index, order-independent, so the scan is branch-free and all
// chunk loads are independent (full MLP, no serial cold-load chains).
// Box traffic: each box read once per block -> ~8 MB total (vs 134 MB when
// scanning per-pred). Exactness: prefix covers box index n (the jittered
// copy of pred n); if a pred has no match in the prefix, a rare block-
// uniform fallback scans the remainder of M.
// Cross-k reduction is deferred to kernel 2 via ws[K][N] (deterministic
// k-ascending sum, bit-identical to ref rounding order; no atomics).
__global__ __launch_bounds__(BLK)
void ue_scan_kernel(const float* __restrict__ pred,    // [N,6]
                    const float* __restrict__ dpreds,  // [K,M,6]
                    const float* __restrict__ dconfs,  // [K,M,C]
                    float* __restrict__ ws_u,          // [K,N]
                    float* __restrict__ ws_mt)         // [K,N]
{
    const int tile = blockIdx.x;
    const int k    = blockIdx.y;
    const int w    = threadIdx.x >> 6;
    const int lane = threadIdx.x & 63;
    const int base = tile * T_PRED;

    __shared__ int s_min[WAVES][T_PRED];

    // pred boxes: wave-uniform broadcast loads
    float px1[T_PRED], py1[T_PRED], px2[T_PRED], py2[T_PRED], a1[T_PRED];
    #pragma unroll
    for (int p = 0; p < T_PRED; ++p) {
        int np = base + p; if (np > N_PRED - 1) np = N_PRED - 1;  // clamp (tail tile)
        const float* pr = pred + np * 6;
        px1[p] = pr[0]; py1[p] = pr[1]; px2[p] = pr[2]; py2[p] = pr[3];
        a1[p] = (px2[p] - px1[p]) * (py2[p] - py1[p]);
    }

    const int kbase = k * M_BOX;
    const float2* dp2 = (const float2*)dpreds;   // row = 3 float2, 8B aligned

    const int maxn = (base + T_PRED - 1 < N_PRED - 1) ? base + T_PRED - 1 : N_PRED - 1;
    const int nchunks = (maxn >> 6) + 1;         // prefix covers box index maxn

    int mi[T_PRED];
    #pragma unroll
    for (int p = 0; p < T_PRED; ++p) mi[p] = IDX_INF;

    // branch-free cooperative prefix scan (chunk base + lane <= 1023 < M)
    for (int c = w; c < nchunks; c += WAVES) {
        const int m = (c << 6) + lane;
        const int i2 = (kbase + m) * 3;
        const float2 a = dp2[i2];
        const float2 b = dp2[i2 + 1];
        const float area2 = (b.x - a.x) * (b.y - a.y);
        #pragma unroll
        for (int p = 0; p < T_PRED; ++p) {
            const float ix1 = fmaxf(px1[p], a.x);
            const float iy1 = fmaxf(py1[p], a.y);
            const float ix2 = fminf(px2[p], b.x);
            const float iy2 = fminf(py2[p], b.y);
            const float inter = fmaxf(ix2 - ix1, 0.0f) * fmaxf(iy2 - iy1, 0.0f);
            const float den = a1[p] + area2 - inter + EPS_IOU;  // ref rounding order
            if ((base + p < N_PRED) && (inter > 0.5f * den)) mi[p] = min(mi[p], m);
        }
    }

    // wave-level min reduce, then publish to LDS
    #pragma unroll
    for (int off = 32; off > 0; off >>= 1) {
        #pragma unroll
        for (int p = 0; p < T_PRED; ++p)
            mi[p] = min(mi[p], __shfl_xor(mi[p], off, 64));
    }
    if (lane == 0) {
        #pragma unroll
        for (int p = 0; p < T_PRED; ++p) s_min[w][p] = mi[p];
    }
    __syncthreads();

    // block-uniform check: any pred unmatched in the prefix? (rare)
    bool need = false;
    #pragma unroll
    for (int p = 0; p < T_PRED; ++p) {
        int v = min(min(s_min[0][p], s_min[1][p]), min(s_min[2][p], s_min[3][p]));
        need = need || ((base + p < N_PRED) && v == IDX_INF);
    }
    if (need) {  // block-uniform fallback: scan remainder, exact semantics
        for (int c = nchunks + w; c < MCHUNKS; c += WAVES) {
            const int m = (c << 6) + lane;
            const bool valid = (m < M_BOX);
            const int i2 = (kbase + (valid ? m : M_BOX - 1)) * 3;
            const float2 a = dp2[i2];
            const float2 b = dp2[i2 + 1];
            const float area2 = (b.x - a.x) * (b.y - a.y);
            #pragma unroll
            for (int p = 0; p < T_PRED; ++p) {
                const float ix1 = fmaxf(px1[p], a.x);
                const float iy1 = fmaxf(py1[p], a.y);
                const float ix2 = fminf(px2[p], b.x);
                const float iy2 = fminf(py2[p], b.y);
                const float inter = fmaxf(ix2 - ix1, 0.0f) * fmaxf(iy2 - iy1, 0.0f);
                const float den = a1[p] + area2 - inter + EPS_IOU;
                if (valid && (base + p < N_PRED) && (inter > 0.5f * den))
                    mi[p] = min(mi[p], m);
            }
        }
        #pragma unroll
        for (int off = 32; off > 0; off >>= 1) {
            #pragma unroll
            for (int p = 0; p < T_PRED; ++p)
                mi[p] = min(mi[p], __shfl_xor(mi[p], off, 64));
        }
        __syncthreads();  // all prior s_min reads done before overwrite
        if (lane == 0) {
            #pragma unroll
            for (int p = 0; p < T_PRED; ++p) s_min[w][p] = mi[p];
        }
        __syncthreads();
    }

    // entropy: wave w handles preds p = w, w+4, w+8, w+12 (math identical
    // to the verified kernel: same expression, same reduce order)
    const float inv_n  = 1.0f / (float)C_CLS;
    const float max_en = -(float)C_CLS * (inv_n * logf(inv_n));  // == log(C)
    #pragma unroll
    for (int j = 0; j < T_PRED / WAVES; ++j) {
        const int p = w + j * WAVES;               // runtime p -> LDS indexing only
        const int n = base + p;
        if (n < N_PRED) {                           // wave-uniform
            const int f = min(min(s_min[0][p], s_min[1][p]),
                              min(s_min[2][p], s_min[3][p]));
            float u = 0.0f, mt = 0.0f;
            if (f != IDX_INF) {                     // wave-uniform
                mt = 1.0f;
                const float* row = dconfs + (size_t)(kbase + f) * C_CLS;
                float local = 0.0f;
                {
                    const float v = row[lane];
                    local -= v * logf(v);
                }
                if (lane < C_CLS - 64) {
                    const float v = row[64 + lane];
                    local -= v * logf(v);
                }
                #pragma unroll
                for (int off = 32; off > 0; off >>= 1)
                    local += __shfl_xor(local, off, 64);
                u = 1.0f - local / max_en;
            }
            if (lane == 0) {
                ws_u[k * N_PRED + n]  = u * mt;
                ws_mt[k * N_PRED + n] = mt;
            }
        }
    }
}

// Kernel 2: deterministic k-ascending reduction (same order as ref / the
// previously verified in-block loop), NaN fallback when no pass matched.
__global__ __launch_bounds__(256)
void ue_final_kernel(const float* __restrict__ ws_u,
                     const float* __restrict__ ws_mt,
                     float* __restrict__ out)
{
    const int n = blockIdx.x * 256 + threadIdx.x;
    if (n >= N_PRED) return;
    float su = 0.0f, cnt = 0.0f;
    #pragma unroll
    for (int kk = 0; kk < K_PASS; ++kk) {
        su  += ws_u[kk * N_PRED + n];
        cnt += ws_mt[kk * N_PRED + n];
    }
    out[n] = (cnt > 0.0f) ? (su / fmaxf(cnt, 1.0f)) : __builtin_nanf("");
}

extern "C" void kernel_launch(void* const* d_in, const int* in_sizes, int n_in,
                              void* d_out, int out_size, void* d_ws, size_t ws_size,
                              hipStream_t stream) {
    const float* pred   = (const float*)d_in[0];   // [N,6]
    const float* dpreds = (const float*)d_in[1];   // [K,M,6]
    const float* dconfs = (const float*)d_in[2];   // [K,M,C]
    float* out  = (float*)d_out;                   // [N]
    float* ws   = (float*)d_ws;                    // >= 2*K*N floats
    float* ws_u  = ws;
    float* ws_mt = ws + K_PASS * N_PRED;

    ue_scan_kernel<<<dim3(NT, K_PASS), dim3(BLK), 0, stream>>>(
        pred, dpreds, dconfs, ws_u, ws_mt);
    ue_final_kernel<<<dim3((N_PRED + 255) / 256), dim3(256), 0, stream>>>(
        ws_u, ws_mt, out);
}

// Round 3
// 67.507 us; speedup vs baseline: 1.1464x; 1.1464x over previous
//
#include <hip/hip_runtime.h>
#include <math.h>

// Problem constants (from reference)
#define N_PRED 1000
#define M_BOX  2000
#define K_PASS 10
#define C_CLS  80
#define EPS_IOU 1e-7f

#define P_PRED 2                       // preds per block (balance: halves worst-wave scan)
#define BLK_T  (K_PASS * 64)           // 640 threads: wave w == pass k
#define N_BLK  (N_PRED / P_PRED)       // 500 blocks -> 5000 waves (~5/SIMD)

#define IDX_INF 0x7fffffff

// Single fused kernel (two launches measurably cost +8us in this harness).
// Block = (2 preds) x (all K passes), wave k owns pass k. Branchless
// ascending prefix scan [0, roundup(nmax+1,64)): no data-dependent break, so
// all chunk loads are independent and pipeline (no serial cold-load chains
// after the poison fill flushes caches each iteration). min-index reduce ==
// first-match semantics. Rare wave-uniform fallback over the remaining boxes
// preserves EXACT semantics. IoU>0.5 is divide-free: inter > 0.5*den with
// den in ref rounding order (identical to the verified absmax==0 kernel).
// New: speculative prefetch of conf row n (the jittered copy index) issued
// before the scan -- first match is w.h.p. n, hiding the ~900-cycle cold row
// load under the scan; exact reload if first != n. Heavy (high-n) blocks
// launch first via reversed block indexing.
__global__ __launch_bounds__(BLK_T)
void ue_cls_kernel(const float* __restrict__ pred,    // [N,6]
                   const float* __restrict__ dpreds,  // [K,M,6]
                   const float* __restrict__ dconfs,  // [K,M,C]
                   float* __restrict__ out)           // [N]
{
    const int k    = threadIdx.x >> 6;
    const int lane = threadIdx.x & 63;
    const int n0   = (N_BLK - 1 - blockIdx.x) * P_PRED;  // heavy blocks first

    __shared__ float s_u[K_PASS][P_PRED];
    __shared__ float s_m[K_PASS][P_PRED];

    // pred boxes (wave-uniform broadcast loads -> s_load)
    float px1[P_PRED], py1[P_PRED], px2[P_PRED], py2[P_PRED], a1[P_PRED];
    #pragma unroll
    for (int p = 0; p < P_PRED; ++p) {
        const float* pr = pred + (n0 + p) * 6;
        px1[p] = pr[0]; py1[p] = pr[1]; px2[p] = pr[2]; py2[p] = pr[3];
        a1[p] = (px2[p] - px1[p]) * (py2[p] - py1[p]);
    }

    const int kbase = k * M_BOX;
    const float2* dp2 = (const float2*)dpreds;  // row = 3 float2, 8B aligned

    // speculative conf-row prefetch for the expected first match (box n0+p)
    float sv0[P_PRED], sv1[P_PRED];
    #pragma unroll
    for (int p = 0; p < P_PRED; ++p) {
        const float* row = dconfs + (size_t)(kbase + n0 + p) * C_CLS;
        sv0[p] = row[lane];
        sv1[p] = (lane < C_CLS - 64) ? row[64 + lane] : 0.0f;
    }

    int firstI[P_PRED];
    #pragma unroll
    for (int p = 0; p < P_PRED; ++p) firstI[p] = IDX_INF;

    // bounded branchless scan: L = roundup(nmax+1, 64) <= 1024 < M, so no
    // bounds checks needed in this loop.
    const int L = (((n0 + P_PRED - 1) >> 6) << 6) + 64;
    for (int c0 = 0; c0 < L; c0 += 64) {
        const int m = c0 + lane;
        const int i2 = (kbase + m) * 3;
        const float2 a = dp2[i2];
        const float2 b = dp2[i2 + 1];
        const float area2 = (b.x - a.x) * (b.y - a.y);
        #pragma unroll
        for (int p = 0; p < P_PRED; ++p) {
            const float ix1 = fmaxf(px1[p], a.x);
            const float iy1 = fmaxf(py1[p], a.y);
            const float ix2 = fminf(px2[p], b.x);
            const float iy2 = fminf(py2[p], b.y);
            const float inter = fmaxf(ix2 - ix1, 0.0f) * fmaxf(iy2 - iy1, 0.0f);
            const float den = a1[p] + area2 - inter + EPS_IOU;  // ref rounding order
            if (inter > 0.5f * den) firstI[p] = min(firstI[p], m);
        }
    }
    #pragma unroll
    for (int off = 32; off > 0; off >>= 1) {
        #pragma unroll
        for (int p = 0; p < P_PRED; ++p)
            firstI[p] = min(firstI[p], __shfl_xor(firstI[p], off, 64));
    }

    // exactness fallback: if any pred unmatched in [0,L), scan the rest.
    bool need = false;
    #pragma unroll
    for (int p = 0; p < P_PRED; ++p) need = need || (firstI[p] == IDX_INF);
    if (need) {  // wave-uniform, rare
        for (int c0 = L; c0 < M_BOX; c0 += 64) {
            const int m = c0 + lane;
            const bool valid = (m < M_BOX);
            const int i2 = (kbase + (valid ? m : M_BOX - 1)) * 3;
            const float2 a = dp2[i2];
            const float2 b = dp2[i2 + 1];
            const float area2 = (b.x - a.x) * (b.y - a.y);
            #pragma unroll
            for (int p = 0; p < P_PRED; ++p) {
                const float ix1 = fmaxf(px1[p], a.x);
                const float iy1 = fmaxf(py1[p], a.y);
                const float ix2 = fminf(px2[p], b.x);
                const float iy2 = fminf(py2[p], b.y);
                const float inter = fmaxf(ix2 - ix1, 0.0f) * fmaxf(iy2 - iy1, 0.0f);
                const float den = a1[p] + area2 - inter + EPS_IOU;
                if (valid && inter > 0.5f * den) firstI[p] = min(firstI[p], m);
            }
        }
        #pragma unroll
        for (int off = 32; off > 0; off >>= 1) {
            #pragma unroll
            for (int p = 0; p < P_PRED; ++p)
                firstI[p] = min(firstI[p], __shfl_xor(firstI[p], off, 64));
        }
    }

    // entropy of the matched class-conf row per pred (identical math to ref)
    const float inv_n  = 1.0f / (float)C_CLS;
    const float max_en = -(float)C_CLS * (inv_n * logf(inv_n));  // == log(C)
    float um[P_PRED], mt[P_PRED];
    #pragma unroll
    for (int p = 0; p < P_PRED; ++p) {
        um[p] = 0.0f; mt[p] = 0.0f;
        if (firstI[p] != IDX_INF) {  // wave-uniform branch
            mt[p] = 1.0f;
            float v0, v1 = 0.0f;
            if (firstI[p] == n0 + p) {          // common case: prefetched row
                v0 = sv0[p]; v1 = sv1[p];
            } else {                             // rare: reload actual row
                const float* row = dconfs + (size_t)(kbase + firstI[p]) * C_CLS;
                v0 = row[lane];
                if (lane < C_CLS - 64) v1 = row[64 + lane];
            }
            float local = -v0 * logf(v0);
            if (lane < C_CLS - 64) local -= v1 * logf(v1);
            #pragma unroll
            for (int off = 32; off > 0; off >>= 1)
                local += __shfl_xor(local, off, 64);
            um[p] = 1.0f - local / max_en;
        }
    }

    if (lane == 0) {
        #pragma unroll
        for (int p = 0; p < P_PRED; ++p) {
            s_u[k][p] = um[p] * mt[p];
            s_m[k][p] = mt[p];
        }
    }
    __syncthreads();

    if (threadIdx.x < P_PRED) {
        const int t = threadIdx.x;
        float cnt = 0.0f, su = 0.0f;
        #pragma unroll
        for (int kk = 0; kk < K_PASS; ++kk) { su += s_u[kk][t]; cnt += s_m[kk][t]; }
        out[n0 + t] = (cnt > 0.0f) ? (su / fmaxf(cnt, 1.0f)) : __builtin_nanf("");
    }
}

extern "C" void kernel_launch(void* const* d_in, const int* in_sizes, int n_in,
                              void* d_out, int out_size, void* d_ws, size_t ws_size,
                              hipStream_t stream) {
    const float* pred   = (const float*)d_in[0];   // [N,6]
    const float* dpreds = (const float*)d_in[1];   // [K,M,6]
    const float* dconfs = (const float*)d_in[2];   // [K,M,C]
    float* out = (float*)d_out;                    // [N]

    ue_cls_kernel<<<dim3(N_BLK), dim3(BLK_T), 0, stream>>>(pred, dpreds, dconfs, out);
}